// Round 16
// baseline (243.561 us; speedup 1.0000x reference)
//
#include <hip/hip_runtime.h>
#include <math.h>

// ---- constants from the reference ----
#define S_SAMPLES 447                      // int(norm([129]*3)/0.5)+1
#define ACT_SHIFT -9.210240366971207f      // log(1/(1-1e-4) - 1)
#define BN_SCALE_C 0.9999950000374997f     // (1+1e-5)^-0.5
#define STEP_VOX 0.015625f                 // STEPSIZE * VOXEL = 0.5 * (2/64)

__device__ __forceinline__ unsigned f2bf_u(float f) {
    unsigned u = __float_as_uint(f);
    return (u + 0x7fffu + ((u >> 16) & 1u)) >> 16;   // RNE, low 16 bits
}
__device__ __forceinline__ float bf2f(unsigned short u) {
    return __uint_as_float(((unsigned)u) << 16);
}
__device__ __forceinline__ float bf_lo(unsigned u) { return __uint_as_float(u << 16); }
__device__ __forceinline__ float bf_hi(unsigned u) { return __uint_as_float(u & 0xffff0000u); }

typedef __attribute__((ext_vector_type(8))) short bf16x8;   // MFMA A/B frag (4 VGPRs)
typedef __attribute__((ext_vector_type(4))) float f32x4;    // MFMA C/D frag

// ============================================================================
// Kernel 0: prep — weight transposes (grid-stride over 64 blocks).
// A-row k-order: [x1(0-63) | grid(64-79) | 0(80-95) | x2(96-159)].
// ============================================================================
__global__ __launch_bounds__(256) void prep_kernel(
    const float* __restrict__ w1, const float* __restrict__ w2,
    const float* __restrict__ w3, const float* __restrict__ b3,
    const float* __restrict__ mw0, const float* __restrict__ mw1,
    const float* __restrict__ mw2,
    unsigned short* __restrict__ w1b, unsigned short* __restrict__ w2b,
    unsigned short* __restrict__ w3b, float* __restrict__ b3p,
    unsigned short* __restrict__ m0t, unsigned short* __restrict__ m1t,
    unsigned short* __restrict__ m2t)
{
    const int gid = blockIdx.x * 256 + threadIdx.x;
    const int gs = gridDim.x * 256;
    for (int idx = gid; idx < 2048; idx += gs) {         // w1b [64 o][32 k]
        const int o = idx >> 5, k = idx & 31;
        w1b[idx] = (k < 16) ? (unsigned short)f2bf_u(w1[o * 16 + k]) : 0;
    }
    for (int idx = gid; idx < 6144; idx += gs) {         // w2b [64 o][96 k]
        const int o = idx / 96, k = idx % 96;
        w2b[idx] = (k < 80) ? (unsigned short)f2bf_u(w2[o * 80 + k]) : 0;
    }
    for (int idx = gid; idx < 20480; idx += gs) {        // w3b [128 n][160 k]
        const int n = idx / 160, k = idx % 160;
        const int s = n >> 4, l = n & 15;
        const int o = l * 8 + s;
        float val = 0.f;
        if (k < 64)       val = w3[o * 144 + k];             // x1 part
        else if (k < 80)  val = w3[o * 144 + 128 + (k - 64)];// grid part
        else if (k >= 96) val = w3[o * 144 + 64 + (k - 96)]; // x2 part
        w3b[idx] = (unsigned short)f2bf_u(val);
    }
    for (int idx = gid; idx < 128; idx += gs) {
        const int o = idx;
        b3p[(o & 7) * 16 + (o >> 3)] = b3[o];
    }
    for (int idx = gid; idx < 4096; idx += gs) {
        const int o = idx >> 6, k = idx & 63;
        m0t[o * 64 + k] = (k < 54) ? (unsigned short)f2bf_u(mw0[k * 64 + o]) : 0;
    }
    for (int idx = gid; idx < 4096; idx += gs) {
        const int o = idx >> 6, k = idx & 63;
        m1t[o * 64 + k] = (unsigned short)f2bf_u(mw1[k * 64 + o]);
    }
    for (int idx = gid; idx < 4096; idx += gs) {
        const int o = idx >> 6, k = idx & 63;
        m2t[o * 64 + k] = (unsigned short)f2bf_u(mw2[k * 64 + o]);
    }
}

// ============================================================================
// Kernel 1: FUSED conv1+conv2+conv3, single-wave workgroups (64 thr = 32
// voxels, 2 m-tiles) — exact round-13 structure (VGPR ~100, proven 57 us).
// __syncthreads() = cheap fence for one-wave blocks. LDS ~11.5 KB.
// ============================================================================
__global__ __launch_bounds__(64) void conv_fused_kernel(
    const float* __restrict__ grid,
    const unsigned short* __restrict__ w1b, const float* __restrict__ b1,
    const float* __restrict__ g1, const float* __restrict__ bb1, const float* __restrict__ a1,
    const unsigned short* __restrict__ w2b, const float* __restrict__ b2,
    const float* __restrict__ g2, const float* __restrict__ bb2, const float* __restrict__ a2,
    const unsigned short* __restrict__ w3b, const float* __restrict__ b3p,
    unsigned short* __restrict__ featb, float* __restrict__ dens)
{
    __shared__ __align__(16) unsigned short AT[32 * 168];   // 10.5 KB (Ct aliases)
    __shared__ float densT[32 * 8];                         // 1 KB
    unsigned short* Ct = AT;
    const int t = threadIdx.x;          // 0..63, one wave
    const int v0 = blockIdx.x * 32;

    // zero cols 80..95 (32 v x 8 dwords)
    for (int idx = t; idx < 256; idx += 64) {
        const int v = idx >> 3, c = idx & 7;
        *(unsigned*)(AT + v * 168 + 80 + c * 2) = 0;
    }
    // grid -> AT cols 64..79: c = 2i + (t>>5), v = t&31
#pragma unroll
    for (int i = 0; i < 8; ++i) {
        const int c = 2 * i + (t >> 5);
        const float gv = grid[(size_t)c * 262144 + v0 + (t & 31)];
        AT[(t & 31) * 168 + 64 + c] = (unsigned short)f2bf_u(gv);
    }
    __syncthreads();

    const int quad = t >> 4, l16 = t & 15;

    // ---- conv1: A cols 64..95 (K=32), out -> cols 0..63 (2mt x 4nt) ----
    {
        f32x4 acc[2][4];
        float gs[4], bb[4], al[4];
#pragma unroll
        for (int nt = 0; nt < 4; ++nt) {
            const int ch = 16 * nt + l16;
            const float bch = b1[ch];
            gs[nt] = BN_SCALE_C * g1[ch]; bb[nt] = bb1[ch]; al[nt] = a1[ch];
#pragma unroll
            for (int mt = 0; mt < 2; ++mt) {
                acc[mt][nt][0] = bch; acc[mt][nt][1] = bch;
                acc[mt][nt][2] = bch; acc[mt][nt][3] = bch;
            }
        }
        const int k0 = 8 * quad;
        bf16x8 a[2], b[4];
#pragma unroll
        for (int mt = 0; mt < 2; ++mt)
            a[mt] = __builtin_bit_cast(bf16x8, *(const uint4*)(AT + (16 * mt + l16) * 168 + 64 + k0));
#pragma unroll
        for (int nt = 0; nt < 4; ++nt)
            b[nt] = __builtin_bit_cast(bf16x8, *(const uint4*)(w1b + (16 * nt + l16) * 32 + k0));
#pragma unroll
        for (int mt = 0; mt < 2; ++mt)
#pragma unroll
            for (int nt = 0; nt < 4; ++nt)
                acc[mt][nt] = __builtin_amdgcn_mfma_f32_16x16x32_bf16(a[mt], b[nt], acc[mt][nt], 0, 0, 0);
        __syncthreads();
#pragma unroll
        for (int mt = 0; mt < 2; ++mt)
#pragma unroll
            for (int nt = 0; nt < 4; ++nt)
#pragma unroll
                for (int reg = 0; reg < 4; ++reg) {
                    float x = acc[mt][nt][reg] * gs[nt] + bb[nt];
                    x = (x >= 0.f) ? x : al[nt] * x;
                    AT[(16 * mt + 4 * quad + reg) * 168 + 16 * nt + l16] = (unsigned short)f2bf_u(x);
                }
    }
    __syncthreads();

    // ---- conv2: A cols 0..95 (K=96), out -> cols 96..159 (2mt x 4nt) ----
    {
        f32x4 acc[2][4];
        float gs[4], bb[4], al[4];
#pragma unroll
        for (int nt = 0; nt < 4; ++nt) {
            const int ch = 16 * nt + l16;
            const float bch = b2[ch];
            gs[nt] = BN_SCALE_C * g2[ch]; bb[nt] = bb2[ch]; al[nt] = a2[ch];
#pragma unroll
            for (int mt = 0; mt < 2; ++mt) {
                acc[mt][nt][0] = bch; acc[mt][nt][1] = bch;
                acc[mt][nt][2] = bch; acc[mt][nt][3] = bch;
            }
        }
#pragma unroll
        for (int kq = 0; kq < 3; ++kq) {
            const int k0 = 32 * kq + 8 * quad;
            bf16x8 a[2], b[4];
#pragma unroll
            for (int mt = 0; mt < 2; ++mt)
                a[mt] = __builtin_bit_cast(bf16x8, *(const uint4*)(AT + (16 * mt + l16) * 168 + k0));
#pragma unroll
            for (int nt = 0; nt < 4; ++nt)
                b[nt] = __builtin_bit_cast(bf16x8, *(const uint4*)(w2b + (16 * nt + l16) * 96 + k0));
#pragma unroll
            for (int mt = 0; mt < 2; ++mt)
#pragma unroll
                for (int nt = 0; nt < 4; ++nt)
                    acc[mt][nt] = __builtin_amdgcn_mfma_f32_16x16x32_bf16(a[mt], b[nt], acc[mt][nt], 0, 0, 0);
        }
        __syncthreads();
#pragma unroll
        for (int mt = 0; mt < 2; ++mt)
#pragma unroll
            for (int nt = 0; nt < 4; ++nt)
#pragma unroll
                for (int reg = 0; reg < 4; ++reg) {
                    float x = acc[mt][nt][reg] * gs[nt] + bb[nt];
                    x = (x >= 0.f) ? x : al[nt] * x;
                    AT[(16 * mt + 4 * quad + reg) * 168 + 96 + 16 * nt + l16] = (unsigned short)f2bf_u(x);
                }
    }
    __syncthreads();

    // ---- conv3: A cols 0..159 (K=160), 2mt x 8nt x 5kq = 80 MFMA ----
    {
        f32x4 acc[2][8];
#pragma unroll
        for (int nt = 0; nt < 8; ++nt) {
            const float bv = b3p[16 * nt + l16];
#pragma unroll
            for (int mt = 0; mt < 2; ++mt) {
                acc[mt][nt][0] = bv; acc[mt][nt][1] = bv;
                acc[mt][nt][2] = bv; acc[mt][nt][3] = bv;
            }
        }
#pragma unroll
        for (int kq = 0; kq < 5; ++kq) {
            const int k0 = 32 * kq + 8 * quad;
            bf16x8 a[2], b[8];
#pragma unroll
            for (int mt = 0; mt < 2; ++mt)
                a[mt] = __builtin_bit_cast(bf16x8, *(const uint4*)(AT + (16 * mt + l16) * 168 + k0));
#pragma unroll
            for (int nt = 0; nt < 8; ++nt)
                b[nt] = __builtin_bit_cast(bf16x8, *(const uint4*)(w3b + (size_t)(16 * nt + l16) * 160 + k0));
#pragma unroll
            for (int mt = 0; mt < 2; ++mt)
#pragma unroll
                for (int nt = 0; nt < 8; ++nt)
                    acc[mt][nt] = __builtin_amdgcn_mfma_f32_16x16x32_bf16(a[mt], b[nt], acc[mt][nt], 0, 0, 0);
        }

        // all conv3 A-reads drained before Ct overwrites AT
        __syncthreads();

        if (l16 == 0) {
#pragma unroll
            for (int mt = 0; mt < 2; ++mt)
#pragma unroll
                for (int nt = 0; nt < 8; ++nt)
#pragma unroll
                    for (int reg = 0; reg < 4; ++reg)
                        densT[(16 * mt + 4 * quad + reg) * 8 + nt] = acc[mt][nt][reg];
        }
#pragma unroll
        for (int mt = 0; mt < 2; ++mt)
#pragma unroll
            for (int nt = 0; nt < 8; ++nt)
#pragma unroll
                for (int reg = 0; reg < 4; ++reg)
                    Ct[(16 * mt + 4 * quad + reg) * 136 + 16 * nt + l16] =
                        (unsigned short)f2bf_u(acc[mt][nt][reg]);
    }
    __syncthreads();

    // epilogue: thread = (voxel, s-half); 16B featb stores + fp32 dens
    const int v = t >> 1, half = t & 1;
    const int vg = v0 + v;
    const int Z = vg & 63, Y = (vg >> 6) & 63, X = vg >> 12;
#pragma unroll
    for (int si = 0; si < 4; ++si) {
        const int s = 4 * half + si;
        const int d2 = (s >> 2) & 1, h2 = (s >> 1) & 1, w2i = s & 1;
        const int ubase = ((2 * X + d2) * 128 + (2 * Y + h2)) * 128 + (2 * Z + w2i);
        const uint4 q0 = *(const uint4*)(Ct + v * 136 + 16 * s);
        const uint4 q1 = *(const uint4*)(Ct + v * 136 + 16 * s + 8);
        *(uint4*)(featb + (size_t)ubase * 16)     = q0;
        *(uint4*)(featb + (size_t)ubase * 16 + 8) = q1;
        dens[ubase] = densT[v * 8 + s];
    }
}

// ============================================================================
// Kernel 2: separable Sobel — three 1-D passes.
// ============================================================================
__global__ __launch_bounds__(256) void sobelZ_kernel(const float* __restrict__ dens,
                                                     float2* __restrict__ zbuf)
{
    const int v = blockIdx.x * 256 + threadIdx.x;
    const int z = v & 127;
    float d[5];
#pragma unroll
    for (int k = 0; k < 5; ++k) {
        const int zz = z + k - 2;
        d[k] = (zz >= 0 && zz < 128) ? dens[v + (k - 2)] : 0.f;
    }
    const float az = d[0] + 4.f * d[1] + 6.f * d[2] + 4.f * d[3] + d[4];
    const float bz = -d[0] - 2.f * d[1] + 2.f * d[3] + d[4];
    zbuf[v] = make_float2(az, bz);
}

__global__ __launch_bounds__(256) void sobelY_kernel(const float2* __restrict__ zbuf,
                                                     float4* __restrict__ cbuf)
{
    const int v = blockIdx.x * 256 + threadIdx.x;
    const int y = (v >> 7) & 127;
    float2 e[5];
#pragma unroll
    for (int j = 0; j < 5; ++j) {
        const int yy = y + j - 2;
        e[j] = (yy >= 0 && yy < 128) ? zbuf[v + (j - 2) * 128] : make_float2(0.f, 0.f);
    }
    const float c1 = e[0].x + 4.f * e[1].x + 6.f * e[2].x + 4.f * e[3].x + e[4].x;
    const float c2 = -e[0].x - 2.f * e[1].x + 2.f * e[3].x + e[4].x;
    const float c3 = e[0].y + 4.f * e[1].y + 6.f * e[2].y + 4.f * e[3].y + e[4].y;
    cbuf[v] = make_float4(c1, c2, c3, 0.f);
}

__global__ __launch_bounds__(256) void sobelX_kernel(const float4* __restrict__ cbuf,
                                                     float* __restrict__ normals)
{
    const int v = blockIdx.x * 256 + threadIdx.x;
    const int x = v >> 14;
    float4 q[5];
#pragma unroll
    for (int i = 0; i < 5; ++i) {
        const int xx = x + i - 2;
        q[i] = (xx >= 0 && xx < 128) ? cbuf[v + (i - 2) * 16384]
                                     : make_float4(0.f, 0.f, 0.f, 0.f);
    }
    float sx = -q[0].x - 2.f * q[1].x + 2.f * q[3].x + q[4].x;
    float sy = q[0].y + 4.f * q[1].y + 6.f * q[2].y + 4.f * q[3].y + q[4].y;
    float sz = q[0].z + 4.f * q[1].z + 6.f * q[2].z + 4.f * q[3].z + q[4].z;
    sx *= (1.f / 72.f); sy *= (1.f / 72.f); sz *= (1.f / 72.f);
    const float n = sqrtf(sx * sx + sy * sy + sz * sz);
    const float inv = 1.f / fmaxf(n, 1e-12f);
    normals[v * 3 + 0] = -sx * inv;
    normals[v * 3 + 1] = -sy * inv;
    normals[v * 3 + 2] = -sz * inv;
}

// ============================================================================
// Kernel 3: per-sample shading, single-wave workgroups (64 thr = 64 samples).
// __syncthreads() fences between layers. act in-place, 9.2 KB LDS.
// ============================================================================
__device__ __forceinline__ void mfma_layer(unsigned short* A,
                                           const unsigned short* __restrict__ Wg,
                                           const float* __restrict__ bias,
                                           const int lane)
{
    const int quad = lane >> 4, l16 = lane & 15;
    f32x4 acc[4][4];
#pragma unroll
    for (int nt = 0; nt < 4; ++nt) {
        const float bv = bias[16 * nt + l16];
#pragma unroll
        for (int mt = 0; mt < 4; ++mt) {
            acc[mt][nt][0] = bv; acc[mt][nt][1] = bv;
            acc[mt][nt][2] = bv; acc[mt][nt][3] = bv;
        }
    }
    bf16x8 a[2][4], b[2][4];
#pragma unroll
    for (int kq = 0; kq < 2; ++kq) {
        const int k0 = 32 * kq + 8 * quad;
#pragma unroll
        for (int mt = 0; mt < 4; ++mt)
            a[kq][mt] = __builtin_bit_cast(bf16x8, *(const uint4*)(A + (16 * mt + l16) * 72 + k0));
#pragma unroll
        for (int nt = 0; nt < 4; ++nt)
            b[kq][nt] = __builtin_bit_cast(bf16x8, *(const uint4*)(Wg + (16 * nt + l16) * 64 + k0));
    }
#pragma unroll
    for (int kq = 0; kq < 2; ++kq)
#pragma unroll
        for (int mt = 0; mt < 4; ++mt)
#pragma unroll
            for (int nt = 0; nt < 4; ++nt)
                acc[mt][nt] = __builtin_amdgcn_mfma_f32_16x16x32_bf16(a[kq][mt], b[kq][nt], acc[mt][nt], 0, 0, 0);
    __syncthreads();   // all reads of A drained before in-place overwrite
#pragma unroll
    for (int mt = 0; mt < 4; ++mt)
#pragma unroll
        for (int nt = 0; nt < 4; ++nt)
#pragma unroll
            for (int reg = 0; reg < 4; ++reg) {
                const float v = fmaxf(acc[mt][nt][reg], 0.f);
                A[(16 * mt + 4 * quad + reg) * 72 + 16 * nt + l16] =
                    (unsigned short)f2bf_u(v);
            }
    __syncthreads();
}

__global__ __launch_bounds__(64) void sample_kernel(
    const float* __restrict__ ro, const float* __restrict__ rd, const float* __restrict__ vd,
    const unsigned short* __restrict__ featb, const float* __restrict__ dens,
    const float* __restrict__ normals,
    const unsigned short* __restrict__ m0t, const float* __restrict__ mb0,
    const unsigned short* __restrict__ m1t, const float* __restrict__ mb1,
    const unsigned short* __restrict__ m2t, const float* __restrict__ mb2,
    const float* __restrict__ mw3, const float* __restrict__ mb3,
    float* __restrict__ sbuf, const int total)
{
    __shared__ __align__(16) unsigned short act[64 * 72];   // 9.2 KB, in-place

    const int t = threadIdx.x;          // 0..63, one wave
    const int s = blockIdx.x * 64 + t;
    const bool live = (s < total);
    bool actv = false;
    float alpha = 0.f, ndx = 0.f, ndy = 0.f, ndz = 0.f;
    float nsx = 0.f, nsy = 0.f, nsz = 0.f, depth = 0.f;
    float hf[64];
#pragma unroll
    for (int q = 0; q < 64; ++q) hf[q] = 0.f;

    if (live) {
        const int r = s / S_SAMPLES;
        const int j = s - r * S_SAMPLES;

        const float ox = ro[r * 3 + 0], oy = ro[r * 3 + 1], oz = ro[r * 3 + 2];
        const float dx = rd[r * 3 + 0], dy = rd[r * 3 + 1], dz = rd[r * 3 + 2];
        const float vx = vd[r * 3 + 0], vy = vd[r * 3 + 1], vz = vd[r * 3 + 2];

        const float vecx = (dx == 0.f) ? 1e-6f : dx;
        const float vecy = (dy == 0.f) ? 1e-6f : dy;
        const float vecz = (dz == 0.f) ? 1e-6f : dz;
        const float rax = (1.f - ox) / vecx, rbx = (-1.f - ox) / vecx;
        const float ray2 = (1.f - oy) / vecy, rby = (-1.f - oy) / vecy;
        const float raz = (1.f - oz) / vecz, rbz = (-1.f - oz) / vecz;
        float tmin = fmaxf(fmaxf(fminf(rax, rbx), fminf(ray2, rby)), fminf(raz, rbz));
        float tmax = fminf(fminf(fmaxf(rax, rbx), fmaxf(ray2, rby)), fmaxf(raz, rbz));
        tmin = fminf(fmaxf(tmin, 0.2f), 6.0f);
        tmax = fminf(fmaxf(tmax, 0.2f), 6.0f);
        const bool mask_ray = (tmax <= tmin);

        const float ndr = sqrtf(dx * dx + dy * dy + dz * dz);
        const float interpx = tmin + (STEP_VOX * (float)j) / ndr;
        const float px = ox + dx * interpx;
        const float py = oy + dy * interpx;
        const float pz = oz + dz * interpx;
        const bool outbox = mask_ray || (px < -1.f) || (px > 1.f) || (py < -1.f) ||
                            (py > 1.f) || (pz < -1.f) || (pz > 1.f);
        actv = !outbox;
        if (actv) {
            const float ux = fminf(fmaxf((px + 1.f) * 63.5f, 0.f), 127.f);
            const float uy = fminf(fmaxf((py + 1.f) * 63.5f, 0.f), 127.f);
            const float uz = fminf(fmaxf((pz + 1.f) * 63.5f, 0.f), 127.f);
            const int ix = min(max((int)floorf(ux), 0), 126);
            const int iy = min(max((int)floorf(uy), 0), 126);
            const int iz = min(max((int)floorf(uz), 0), 126);
            const float fx = ux - (float)ix, fy = uy - (float)iy, fz = uz - (float)iz;

            float lat[15];
#pragma unroll
            for (int q = 0; q < 15; ++q) lat[q] = 0.f;
            float na0 = 0.f, na1 = 0.f, na2 = 0.f;
            float c0v[8];
#pragma unroll
            for (int cn = 0; cn < 8; ++cn) {
                const int adx = cn >> 2, ady = (cn >> 1) & 1, adz = cn & 1;
                const int vox = ((ix + adx) * 128 + (iy + ady)) * 128 + (iz + adz);
                const float w = (adx ? fx : 1.f - fx) * (ady ? fy : 1.f - fy) * (adz ? fz : 1.f - fz);
                c0v[cn] = dens[vox];
                const uint4* cp = (const uint4*)(featb + (size_t)vox * 16);
                const uint4 q0 = cp[0], q1 = cp[1];
                lat[0]  = fmaf(w, bf_hi(q0.x), lat[0]);
                lat[1]  = fmaf(w, bf_lo(q0.y), lat[1]);
                lat[2]  = fmaf(w, bf_hi(q0.y), lat[2]);
                lat[3]  = fmaf(w, bf_lo(q0.z), lat[3]);
                lat[4]  = fmaf(w, bf_hi(q0.z), lat[4]);
                lat[5]  = fmaf(w, bf_lo(q0.w), lat[5]);
                lat[6]  = fmaf(w, bf_hi(q0.w), lat[6]);
                lat[7]  = fmaf(w, bf_lo(q1.x), lat[7]);
                lat[8]  = fmaf(w, bf_hi(q1.x), lat[8]);
                lat[9]  = fmaf(w, bf_lo(q1.y), lat[9]);
                lat[10] = fmaf(w, bf_hi(q1.y), lat[10]);
                lat[11] = fmaf(w, bf_lo(q1.z), lat[11]);
                lat[12] = fmaf(w, bf_hi(q1.z), lat[12]);
                lat[13] = fmaf(w, bf_lo(q1.w), lat[13]);
                lat[14] = fmaf(w, bf_hi(q1.w), lat[14]);
                const float* np_ = normals + (size_t)vox * 3;
                na0 = fmaf(w, np_[0], na0);
                na1 = fmaf(w, np_[1], na1);
                na2 = fmaf(w, np_[2], na2);
            }

            const float c00 = c0v[0] * (1.f - fz) + c0v[1] * fz;
            const float c01 = c0v[2] * (1.f - fz) + c0v[3] * fz;
            const float c10 = c0v[4] * (1.f - fz) + c0v[5] * fz;
            const float c11 = c0v[6] * (1.f - fz) + c0v[7] * fz;
            const float e0 = c00 * (1.f - fy) + c01 * fy;
            const float e1 = c10 * (1.f - fy) + c11 * fy;
            const float d0 = e0 * (1.f - fx) + e1 * fx;
            const float dfx = e1 - e0;
            const float dfy = (c01 - c00) * (1.f - fx) + (c11 - c10) * fx;
            const float dfz = ((c0v[1] - c0v[0]) * (1.f - fy) + (c0v[3] - c0v[2]) * fy) * (1.f - fx)
                            + ((c0v[5] - c0v[4]) * (1.f - fy) + (c0v[7] - c0v[6]) * fy) * fx;

            const float zin = d0 + ACT_SHIFT;
            const float splus = fmaxf(zin, 0.f) + log1pf(__expf(-fabsf(zin)));
            const float e = __expf(-splus * 0.5f);
            alpha = 1.f - e;
            const float sig = 1.f / (1.f + __expf(-zin));
            const float dad = e * 0.5f * sig;
            const float gx = dad * dfx * 63.5f;
            const float gy = dad * dfy * 63.5f;
            const float gz = dad * dfz * 63.5f;
            const float gn = sqrtf(gx * gx + gy * gy + gz * gz);
            const float gi = 1.f / fmaxf(gn, 1e-12f);
            ndx = -gx * gi; ndy = -gy * gi; ndz = -gz * gi;

            const float nn = sqrtf(na0 * na0 + na1 * na1 + na2 * na2);
            const float ni = 1.f / fmaxf(nn, 1e-12f);
            nsx = -na0 * ni; nsy = -na1 * ni; nsz = -na2 * ni;

            const float dotv = -(vx * ndx + vy * ndy + vz * ndz);
            const float rx = 2.f * dotv * ndx + vx;
            const float ry = 2.f * dotv * ndy + vy;
            const float rz = 2.f * dotv * ndz + vz;

#pragma unroll
            for (int q = 0; q < 15; ++q) hf[q] = lat[q];
            hf[15] = rx; hf[16] = ry; hf[17] = rz;
#pragma unroll
            for (int fi = 0; fi < 6; ++fi) {
                const float fr = (float)(1 << fi);
                hf[18 + fi * 6 + 0] = __sinf(rx * fr);
                hf[18 + fi * 6 + 1] = __sinf(ry * fr);
                hf[18 + fi * 6 + 2] = __sinf(rz * fr);
                hf[18 + fi * 6 + 3] = __cosf(rx * fr);
                hf[18 + fi * 6 + 4] = __cosf(ry * fr);
                hf[18 + fi * 6 + 5] = __cosf(rz * fr);
            }
            depth = interpx * ndr;
        }
    }

#pragma unroll
    for (int q = 0; q < 8; ++q) {
        uint4 st;
        st.x = f2bf_u(hf[8 * q + 0]) | (f2bf_u(hf[8 * q + 1]) << 16);
        st.y = f2bf_u(hf[8 * q + 2]) | (f2bf_u(hf[8 * q + 3]) << 16);
        st.z = f2bf_u(hf[8 * q + 4]) | (f2bf_u(hf[8 * q + 5]) << 16);
        st.w = f2bf_u(hf[8 * q + 6]) | (f2bf_u(hf[8 * q + 7]) << 16);
        *(uint4*)(act + t * 72 + 8 * q) = st;
    }
    __syncthreads();

    mfma_layer(act, m0t, mb0, t);
    mfma_layer(act, m1t, mb1, t);
    mfma_layer(act, m2t, mb2, t);

    if (live) {
        float* so = sbuf + (size_t)s * 12;
        if (actv) {
            float r0 = mb3[0], r1 = mb3[1], r2 = mb3[2];
            const unsigned short* hr = act + t * 72;
#pragma unroll
            for (int c8 = 0; c8 < 8; ++c8) {
                const uint4 hu = *(const uint4*)(hr + 8 * c8);
                const float h[8] = {bf_lo(hu.x), bf_hi(hu.x), bf_lo(hu.y), bf_hi(hu.y),
                                    bf_lo(hu.z), bf_hi(hu.z), bf_lo(hu.w), bf_hi(hu.w)};
#pragma unroll
                for (int u = 0; u < 8; ++u) {
                    const int c = 8 * c8 + u;
                    r0 = fmaf(h[u], mw3[c * 3 + 0], r0);
                    r1 = fmaf(h[u], mw3[c * 3 + 1], r1);
                    r2 = fmaf(h[u], mw3[c * 3 + 2], r2);
                }
            }
            so[0] = alpha;
            so[1] = 1.f / (1.f + __expf(-r0));
            so[2] = 1.f / (1.f + __expf(-r1));
            so[3] = 1.f / (1.f + __expf(-r2));
            so[4] = ndx; so[5] = ndy; so[6] = ndz;
            so[7] = nsx; so[8] = nsy; so[9] = nsz;
            so[10] = depth;
            so[11] = 0.f;
        } else {
#pragma unroll
            for (int q = 0; q < 12; ++q) so[q] = 0.f;
        }
    }
}

// ============================================================================
// Kernel 4: per-ray compositing — COALESCED chunk-strided single pass.
// Chunk i: lane l reads sample 64i+l as 3 aligned float4 (wave reads 3 KB
// contiguous). Per-chunk shfl_up product scan; uniform running transmittance
// R across chunks; all 11 weighted sums in the same pass.
// ============================================================================
__global__ __launch_bounds__(64) void reduce_kernel(const float* __restrict__ sbuf,
                                                    float* __restrict__ out)
{
    const int r = blockIdx.x;
    const int lane = threadIdx.x;
    const int nchunks = (S_SAMPLES + 63) / 64;   // 7

    float R = 1.f;   // product of factors in all previous chunks (wave-uniform)
    float s0 = 0, s1 = 0, s2 = 0, s3 = 0, s4 = 0, s5 = 0, s6 = 0, s7 = 0, s8 = 0, s9 = 0, s10 = 0;

    for (int i = 0; i < nchunks; ++i) {
        const int j = i * 64 + lane;
        float4 q0 = make_float4(0.f, 0.f, 0.f, 0.f);
        float4 q1 = make_float4(0.f, 0.f, 0.f, 0.f);
        float4 q2 = make_float4(0.f, 0.f, 0.f, 0.f);
        float a = 0.f, fac = 1.f;
        if (j < S_SAMPLES) {
            const float* sp_ = sbuf + ((size_t)r * S_SAMPLES + j) * 12;
            q0 = *(const float4*)sp_;          // alpha, rgb0, rgb1, rgb2
            q1 = *(const float4*)(sp_ + 4);    // ndx, ndy, ndz, nsx
            q2 = *(const float4*)(sp_ + 8);    // nsy, nsz, depth, pad
            a = q0.x;
            fac = fmaxf(1.f - a, 1e-10f);
        }
        // inclusive product scan of fac within the wave
        float scan = fac;
#pragma unroll
        for (int off = 1; off < 64; off <<= 1) {
            const float nv = __shfl_up(scan, (unsigned)off, 64);
            if (lane >= off) scan *= nv;
        }
        float pref = __shfl_up(scan, 1u, 64);
        if (lane == 0) pref = 1.f;
        pref *= R;
        const float w = a * pref;
        s0 = fmaf(w, q0.y, s0);
        s1 = fmaf(w, q0.z, s1);
        s2 = fmaf(w, q0.w, s2);
        s3 = fmaf(w, q2.z, s3);     // depth
        s4 += w;
        s5 = fmaf(w, q1.x, s5);     // nd
        s6 = fmaf(w, q1.y, s6);
        s7 = fmaf(w, q1.z, s7);
        s8 = fmaf(w, q1.w, s8);     // ns
        s9 = fmaf(w, q2.x, s9);
        s10 = fmaf(w, q2.y, s10);
        R *= __shfl(scan, 63, 64);  // fold this chunk's total into R
    }

#pragma unroll
    for (int m = 32; m >= 1; m >>= 1) {
        s0 += __shfl_xor(s0, m, 64);
        s1 += __shfl_xor(s1, m, 64);
        s2 += __shfl_xor(s2, m, 64);
        s3 += __shfl_xor(s3, m, 64);
        s4 += __shfl_xor(s4, m, 64);
        s5 += __shfl_xor(s5, m, 64);
        s6 += __shfl_xor(s6, m, 64);
        s7 += __shfl_xor(s7, m, 64);
        s8 += __shfl_xor(s8, m, 64);
        s9 += __shfl_xor(s9, m, 64);
        s10 += __shfl_xor(s10, m, 64);
    }
    if (lane == 0) {
        const float total = R;               // alphainv_last
        const float dm = s3 + total * 6.0f;
        out[r * 12 + 0] = s0 + total;
        out[r * 12 + 1] = s1 + total;
        out[r * 12 + 2] = s2 + total;
        out[r * 12 + 3] = dm;
        out[r * 12 + 4] = 1.f / dm;
        out[r * 12 + 5] = s4;
        out[r * 12 + 6] = s5; out[r * 12 + 7] = s6; out[r * 12 + 8] = s7;
        out[r * 12 + 9] = s8; out[r * 12 + 10] = s9; out[r * 12 + 11] = s10;
    }
}

// ============================================================================
extern "C" void kernel_launch(void* const* d_in, const int* in_sizes, int n_in,
                              void* d_out, int out_size, void* d_ws, size_t ws_size,
                              hipStream_t stream)
{
    (void)n_in; (void)out_size; (void)ws_size;
    const float* rays_o   = (const float*)d_in[0];
    const float* rays_d   = (const float*)d_in[1];
    const float* viewdirs = (const float*)d_in[2];
    const float* grid     = (const float*)d_in[3];
    const float* c1_w  = (const float*)d_in[4];
    const float* c1_b  = (const float*)d_in[5];
    const float* bn1_g = (const float*)d_in[6];
    const float* bn1_b = (const float*)d_in[7];
    const float* pr1_a = (const float*)d_in[8];
    const float* c2_w  = (const float*)d_in[9];
    const float* c2_b  = (const float*)d_in[10];
    const float* bn2_g = (const float*)d_in[11];
    const float* bn2_b = (const float*)d_in[12];
    const float* pr2_a = (const float*)d_in[13];
    const float* c3_w  = (const float*)d_in[14];
    const float* c3_b  = (const float*)d_in[15];
    const float* mw0 = (const float*)d_in[16];
    const float* mb0 = (const float*)d_in[17];
    const float* mw1 = (const float*)d_in[18];
    const float* mb1 = (const float*)d_in[19];
    const float* mw2 = (const float*)d_in[20];
    const float* mb2 = (const float*)d_in[21];
    const float* mw3 = (const float*)d_in[22];
    const float* mb3 = (const float*)d_in[23];

    const int N = in_sizes[0] / 3;   // 1024 rays
    const int total = N * S_SAMPLES;

    // ws layout (float units):
    // featb [0,16777216) | dens [16777216,18874368) |
    // normals [18874368,25165824) | zbuf f2 [25165824,29360128) |
    // cbuf f4 [29360128,37748736) | sbuf [39845888,45337600) | weights after
    float* wsf = (float*)d_ws;
    unsigned short* featb = (unsigned short*)wsf;
    float* dens    = wsf + (size_t)16777216;
    float* normals = wsf + (size_t)18874368;
    float2* zbuf   = (float2*)(wsf + (size_t)25165824);
    float4* cbuf   = (float4*)(wsf + (size_t)29360128);
    float* sbuf    = wsf + (size_t)39845888;
    float* b3p = wsf + (size_t)45337600;
    unsigned short* w1b = (unsigned short*)(wsf + (size_t)45337728);   // 2048 bf16
    unsigned short* w2b = (unsigned short*)(wsf + (size_t)45338752);   // 6144 bf16
    unsigned short* w3b = (unsigned short*)(wsf + (size_t)45341824);   // 20480 bf16
    unsigned short* m0t = (unsigned short*)(wsf + (size_t)45352064);
    unsigned short* m1t = (unsigned short*)(wsf + (size_t)45354112);
    unsigned short* m2t = (unsigned short*)(wsf + (size_t)45356160);

    prep_kernel<<<64, 256, 0, stream>>>(c1_w, c2_w, c3_w, c3_b, mw0, mw1, mw2,
                                        w1b, w2b, w3b, b3p, m0t, m1t, m2t);
    conv_fused_kernel<<<8192, 64, 0, stream>>>(grid, w1b, c1_b, bn1_g, bn1_b, pr1_a,
                                               w2b, c2_b, bn2_g, bn2_b, pr2_a,
                                               w3b, b3p, featb, dens);
    sobelZ_kernel<<<8192, 256, 0, stream>>>(dens, zbuf);
    sobelY_kernel<<<8192, 256, 0, stream>>>(zbuf, cbuf);
    sobelX_kernel<<<8192, 256, 0, stream>>>(cbuf, normals);
    const int sblocks = (total + 63) / 64;
    sample_kernel<<<sblocks, 64, 0, stream>>>(rays_o, rays_d, viewdirs, featb, dens, normals,
                                              m0t, mb0, m1t, mb1, m2t, mb2, mw3, mb3,
                                              sbuf, total);
    reduce_kernel<<<N, 64, 0, stream>>>(sbuf, (float*)d_out);
}

// Round 17
// 241.302 us; speedup vs baseline: 1.0094x; 1.0094x over previous
//
#include <hip/hip_runtime.h>
#include <math.h>

// ---- constants from the reference ----
#define S_SAMPLES 447                      // int(norm([129]*3)/0.5)+1
#define ACT_SHIFT -9.210240366971207f      // log(1/(1-1e-4) - 1)
#define BN_SCALE_C 0.9999950000374997f     // (1+1e-5)^-0.5
#define STEP_VOX 0.015625f                 // STEPSIZE * VOXEL = 0.5 * (2/64)

__device__ __forceinline__ unsigned f2bf_u(float f) {
    unsigned u = __float_as_uint(f);
    return (u + 0x7fffu + ((u >> 16) & 1u)) >> 16;   // RNE, low 16 bits
}
__device__ __forceinline__ float bf2f(unsigned short u) {
    return __uint_as_float(((unsigned)u) << 16);
}
__device__ __forceinline__ float bf_lo(unsigned u) { return __uint_as_float(u << 16); }
__device__ __forceinline__ float bf_hi(unsigned u) { return __uint_as_float(u & 0xffff0000u); }

typedef __attribute__((ext_vector_type(8))) short bf16x8;   // MFMA A/B frag (4 VGPRs)
typedef __attribute__((ext_vector_type(4))) float f32x4;    // MFMA C/D frag

// ============================================================================
// Kernel 0: prep — weight transposes (grid-stride over 64 blocks).
// A-row k-order: [x1(0-63) | grid(64-79) | 0(80-95) | x2(96-159)].
// ============================================================================
__global__ __launch_bounds__(256) void prep_kernel(
    const float* __restrict__ w1, const float* __restrict__ w2,
    const float* __restrict__ w3, const float* __restrict__ b3,
    const float* __restrict__ mw0, const float* __restrict__ mw1,
    const float* __restrict__ mw2,
    unsigned short* __restrict__ w1b, unsigned short* __restrict__ w2b,
    unsigned short* __restrict__ w3b, float* __restrict__ b3p,
    unsigned short* __restrict__ m0t, unsigned short* __restrict__ m1t,
    unsigned short* __restrict__ m2t)
{
    const int gid = blockIdx.x * 256 + threadIdx.x;
    const int gs = gridDim.x * 256;
    for (int idx = gid; idx < 2048; idx += gs) {         // w1b [64 o][32 k]
        const int o = idx >> 5, k = idx & 31;
        w1b[idx] = (k < 16) ? (unsigned short)f2bf_u(w1[o * 16 + k]) : 0;
    }
    for (int idx = gid; idx < 6144; idx += gs) {         // w2b [64 o][96 k]
        const int o = idx / 96, k = idx % 96;
        w2b[idx] = (k < 80) ? (unsigned short)f2bf_u(w2[o * 80 + k]) : 0;
    }
    for (int idx = gid; idx < 20480; idx += gs) {        // w3b [128 n][160 k]
        const int n = idx / 160, k = idx % 160;
        const int s = n >> 4, l = n & 15;
        const int o = l * 8 + s;
        float val = 0.f;
        if (k < 64)       val = w3[o * 144 + k];             // x1 part
        else if (k < 80)  val = w3[o * 144 + 128 + (k - 64)];// grid part
        else if (k >= 96) val = w3[o * 144 + 64 + (k - 96)]; // x2 part
        w3b[idx] = (unsigned short)f2bf_u(val);
    }
    for (int idx = gid; idx < 128; idx += gs) {
        const int o = idx;
        b3p[(o & 7) * 16 + (o >> 3)] = b3[o];
    }
    for (int idx = gid; idx < 4096; idx += gs) {
        const int o = idx >> 6, k = idx & 63;
        m0t[o * 64 + k] = (k < 54) ? (unsigned short)f2bf_u(mw0[k * 64 + o]) : 0;
    }
    for (int idx = gid; idx < 4096; idx += gs) {
        const int o = idx >> 6, k = idx & 63;
        m1t[o * 64 + k] = (unsigned short)f2bf_u(mw1[k * 64 + o]);
    }
    for (int idx = gid; idx < 4096; idx += gs) {
        const int o = idx >> 6, k = idx & 63;
        m2t[o * 64 + k] = (unsigned short)f2bf_u(mw2[k * 64 + o]);
    }
}

// ============================================================================
// Kernel 1: FUSED conv1+conv2+conv3, single-wave workgroups (64 thr = 32
// voxels, 2 m-tiles) — exact round-13 structure (VGPR ~100, proven 57 us).
// __syncthreads() = cheap fence for one-wave blocks. LDS ~11.5 KB.
// ============================================================================
__global__ __launch_bounds__(64) void conv_fused_kernel(
    const float* __restrict__ grid,
    const unsigned short* __restrict__ w1b, const float* __restrict__ b1,
    const float* __restrict__ g1, const float* __restrict__ bb1, const float* __restrict__ a1,
    const unsigned short* __restrict__ w2b, const float* __restrict__ b2,
    const float* __restrict__ g2, const float* __restrict__ bb2, const float* __restrict__ a2,
    const unsigned short* __restrict__ w3b, const float* __restrict__ b3p,
    unsigned short* __restrict__ featb, float* __restrict__ dens)
{
    __shared__ __align__(16) unsigned short AT[32 * 168];   // 10.5 KB (Ct aliases)
    __shared__ float densT[32 * 8];                         // 1 KB
    unsigned short* Ct = AT;
    const int t = threadIdx.x;          // 0..63, one wave
    const int v0 = blockIdx.x * 32;

    // zero cols 80..95 (32 v x 8 dwords)
    for (int idx = t; idx < 256; idx += 64) {
        const int v = idx >> 3, c = idx & 7;
        *(unsigned*)(AT + v * 168 + 80 + c * 2) = 0;
    }
    // grid -> AT cols 64..79: c = 2i + (t>>5), v = t&31
#pragma unroll
    for (int i = 0; i < 8; ++i) {
        const int c = 2 * i + (t >> 5);
        const float gv = grid[(size_t)c * 262144 + v0 + (t & 31)];
        AT[(t & 31) * 168 + 64 + c] = (unsigned short)f2bf_u(gv);
    }
    __syncthreads();

    const int quad = t >> 4, l16 = t & 15;

    // ---- conv1: A cols 64..95 (K=32), out -> cols 0..63 (2mt x 4nt) ----
    {
        f32x4 acc[2][4];
        float gs[4], bb[4], al[4];
#pragma unroll
        for (int nt = 0; nt < 4; ++nt) {
            const int ch = 16 * nt + l16;
            const float bch = b1[ch];
            gs[nt] = BN_SCALE_C * g1[ch]; bb[nt] = bb1[ch]; al[nt] = a1[ch];
#pragma unroll
            for (int mt = 0; mt < 2; ++mt) {
                acc[mt][nt][0] = bch; acc[mt][nt][1] = bch;
                acc[mt][nt][2] = bch; acc[mt][nt][3] = bch;
            }
        }
        const int k0 = 8 * quad;
        bf16x8 a[2], b[4];
#pragma unroll
        for (int mt = 0; mt < 2; ++mt)
            a[mt] = __builtin_bit_cast(bf16x8, *(const uint4*)(AT + (16 * mt + l16) * 168 + 64 + k0));
#pragma unroll
        for (int nt = 0; nt < 4; ++nt)
            b[nt] = __builtin_bit_cast(bf16x8, *(const uint4*)(w1b + (16 * nt + l16) * 32 + k0));
#pragma unroll
        for (int mt = 0; mt < 2; ++mt)
#pragma unroll
            for (int nt = 0; nt < 4; ++nt)
                acc[mt][nt] = __builtin_amdgcn_mfma_f32_16x16x32_bf16(a[mt], b[nt], acc[mt][nt], 0, 0, 0);
        __syncthreads();
#pragma unroll
        for (int mt = 0; mt < 2; ++mt)
#pragma unroll
            for (int nt = 0; nt < 4; ++nt)
#pragma unroll
                for (int reg = 0; reg < 4; ++reg) {
                    float x = acc[mt][nt][reg] * gs[nt] + bb[nt];
                    x = (x >= 0.f) ? x : al[nt] * x;
                    AT[(16 * mt + 4 * quad + reg) * 168 + 16 * nt + l16] = (unsigned short)f2bf_u(x);
                }
    }
    __syncthreads();

    // ---- conv2: A cols 0..95 (K=96), out -> cols 96..159 (2mt x 4nt) ----
    {
        f32x4 acc[2][4];
        float gs[4], bb[4], al[4];
#pragma unroll
        for (int nt = 0; nt < 4; ++nt) {
            const int ch = 16 * nt + l16;
            const float bch = b2[ch];
            gs[nt] = BN_SCALE_C * g2[ch]; bb[nt] = bb2[ch]; al[nt] = a2[ch];
#pragma unroll
            for (int mt = 0; mt < 2; ++mt) {
                acc[mt][nt][0] = bch; acc[mt][nt][1] = bch;
                acc[mt][nt][2] = bch; acc[mt][nt][3] = bch;
            }
        }
#pragma unroll
        for (int kq = 0; kq < 3; ++kq) {
            const int k0 = 32 * kq + 8 * quad;
            bf16x8 a[2], b[4];
#pragma unroll
            for (int mt = 0; mt < 2; ++mt)
                a[mt] = __builtin_bit_cast(bf16x8, *(const uint4*)(AT + (16 * mt + l16) * 168 + k0));
#pragma unroll
            for (int nt = 0; nt < 4; ++nt)
                b[nt] = __builtin_bit_cast(bf16x8, *(const uint4*)(w2b + (16 * nt + l16) * 96 + k0));
#pragma unroll
            for (int mt = 0; mt < 2; ++mt)
#pragma unroll
                for (int nt = 0; nt < 4; ++nt)
                    acc[mt][nt] = __builtin_amdgcn_mfma_f32_16x16x32_bf16(a[mt], b[nt], acc[mt][nt], 0, 0, 0);
        }
        __syncthreads();
#pragma unroll
        for (int mt = 0; mt < 2; ++mt)
#pragma unroll
            for (int nt = 0; nt < 4; ++nt)
#pragma unroll
                for (int reg = 0; reg < 4; ++reg) {
                    float x = acc[mt][nt][reg] * gs[nt] + bb[nt];
                    x = (x >= 0.f) ? x : al[nt] * x;
                    AT[(16 * mt + 4 * quad + reg) * 168 + 96 + 16 * nt + l16] = (unsigned short)f2bf_u(x);
                }
    }
    __syncthreads();

    // ---- conv3: A cols 0..159 (K=160), 2mt x 8nt x 5kq = 80 MFMA ----
    {
        f32x4 acc[2][8];
#pragma unroll
        for (int nt = 0; nt < 8; ++nt) {
            const float bv = b3p[16 * nt + l16];
#pragma unroll
            for (int mt = 0; mt < 2; ++mt) {
                acc[mt][nt][0] = bv; acc[mt][nt][1] = bv;
                acc[mt][nt][2] = bv; acc[mt][nt][3] = bv;
            }
        }
#pragma unroll
        for (int kq = 0; kq < 5; ++kq) {
            const int k0 = 32 * kq + 8 * quad;
            bf16x8 a[2], b[8];
#pragma unroll
            for (int mt = 0; mt < 2; ++mt)
                a[mt] = __builtin_bit_cast(bf16x8, *(const uint4*)(AT + (16 * mt + l16) * 168 + k0));
#pragma unroll
            for (int nt = 0; nt < 8; ++nt)
                b[nt] = __builtin_bit_cast(bf16x8, *(const uint4*)(w3b + (size_t)(16 * nt + l16) * 160 + k0));
#pragma unroll
            for (int mt = 0; mt < 2; ++mt)
#pragma unroll
                for (int nt = 0; nt < 8; ++nt)
                    acc[mt][nt] = __builtin_amdgcn_mfma_f32_16x16x32_bf16(a[mt], b[nt], acc[mt][nt], 0, 0, 0);
        }

        // all conv3 A-reads drained before Ct overwrites AT
        __syncthreads();

        if (l16 == 0) {
#pragma unroll
            for (int mt = 0; mt < 2; ++mt)
#pragma unroll
                for (int nt = 0; nt < 8; ++nt)
#pragma unroll
                    for (int reg = 0; reg < 4; ++reg)
                        densT[(16 * mt + 4 * quad + reg) * 8 + nt] = acc[mt][nt][reg];
        }
#pragma unroll
        for (int mt = 0; mt < 2; ++mt)
#pragma unroll
            for (int nt = 0; nt < 8; ++nt)
#pragma unroll
                for (int reg = 0; reg < 4; ++reg)
                    Ct[(16 * mt + 4 * quad + reg) * 136 + 16 * nt + l16] =
                        (unsigned short)f2bf_u(acc[mt][nt][reg]);
    }
    __syncthreads();

    // epilogue: thread = (voxel, s-half); 16B featb stores + fp32 dens
    const int v = t >> 1, half = t & 1;
    const int vg = v0 + v;
    const int Z = vg & 63, Y = (vg >> 6) & 63, X = vg >> 12;
#pragma unroll
    for (int si = 0; si < 4; ++si) {
        const int s = 4 * half + si;
        const int d2 = (s >> 2) & 1, h2 = (s >> 1) & 1, w2i = s & 1;
        const int ubase = ((2 * X + d2) * 128 + (2 * Y + h2)) * 128 + (2 * Z + w2i);
        const uint4 q0 = *(const uint4*)(Ct + v * 136 + 16 * s);
        const uint4 q1 = *(const uint4*)(Ct + v * 136 + 16 * s + 8);
        *(uint4*)(featb + (size_t)ubase * 16)     = q0;
        *(uint4*)(featb + (size_t)ubase * 16 + 8) = q1;
        dens[ubase] = densT[v * 8 + s];
    }
}

// ============================================================================
// Kernel 2: separable Sobel — three 1-D passes. Final pass packs
// nrm4[v] = (nx, ny, nz, dens[v]) so sample's gather is one float4/corner.
// ============================================================================
__global__ __launch_bounds__(256) void sobelZ_kernel(const float* __restrict__ dens,
                                                     float2* __restrict__ zbuf)
{
    const int v = blockIdx.x * 256 + threadIdx.x;
    const int z = v & 127;
    float d[5];
#pragma unroll
    for (int k = 0; k < 5; ++k) {
        const int zz = z + k - 2;
        d[k] = (zz >= 0 && zz < 128) ? dens[v + (k - 2)] : 0.f;
    }
    const float az = d[0] + 4.f * d[1] + 6.f * d[2] + 4.f * d[3] + d[4];
    const float bz = -d[0] - 2.f * d[1] + 2.f * d[3] + d[4];
    zbuf[v] = make_float2(az, bz);
}

__global__ __launch_bounds__(256) void sobelY_kernel(const float2* __restrict__ zbuf,
                                                     float4* __restrict__ cbuf)
{
    const int v = blockIdx.x * 256 + threadIdx.x;
    const int y = (v >> 7) & 127;
    float2 e[5];
#pragma unroll
    for (int j = 0; j < 5; ++j) {
        const int yy = y + j - 2;
        e[j] = (yy >= 0 && yy < 128) ? zbuf[v + (j - 2) * 128] : make_float2(0.f, 0.f);
    }
    const float c1 = e[0].x + 4.f * e[1].x + 6.f * e[2].x + 4.f * e[3].x + e[4].x;
    const float c2 = -e[0].x - 2.f * e[1].x + 2.f * e[3].x + e[4].x;
    const float c3 = e[0].y + 4.f * e[1].y + 6.f * e[2].y + 4.f * e[3].y + e[4].y;
    cbuf[v] = make_float4(c1, c2, c3, 0.f);
}

__global__ __launch_bounds__(256) void sobelX_kernel(const float4* __restrict__ cbuf,
                                                     const float* __restrict__ dens,
                                                     float4* __restrict__ nrm4)
{
    const int v = blockIdx.x * 256 + threadIdx.x;
    const int x = v >> 14;
    float4 q[5];
#pragma unroll
    for (int i = 0; i < 5; ++i) {
        const int xx = x + i - 2;
        q[i] = (xx >= 0 && xx < 128) ? cbuf[v + (i - 2) * 16384]
                                     : make_float4(0.f, 0.f, 0.f, 0.f);
    }
    float sx = -q[0].x - 2.f * q[1].x + 2.f * q[3].x + q[4].x;
    float sy = q[0].y + 4.f * q[1].y + 6.f * q[2].y + 4.f * q[3].y + q[4].y;
    float sz = q[0].z + 4.f * q[1].z + 6.f * q[2].z + 4.f * q[3].z + q[4].z;
    sx *= (1.f / 72.f); sy *= (1.f / 72.f); sz *= (1.f / 72.f);
    const float n = sqrtf(sx * sx + sy * sy + sz * sz);
    const float inv = 1.f / fmaxf(n, 1e-12f);
    nrm4[v] = make_float4(-sx * inv, -sy * inv, -sz * inv, dens[v]);
}

// ============================================================================
// Kernel 3: per-sample shading, single-wave workgroups (64 thr = 64 samples).
// Gather = 3 loads/corner (2x uint4 featb + 1x float4 nrm4 [normals+dens]).
// __syncthreads() fences between layers. act in-place, 9.2 KB LDS.
// ============================================================================
__device__ __forceinline__ void mfma_layer(unsigned short* A,
                                           const unsigned short* __restrict__ Wg,
                                           const float* __restrict__ bias,
                                           const int lane)
{
    const int quad = lane >> 4, l16 = lane & 15;
    f32x4 acc[4][4];
#pragma unroll
    for (int nt = 0; nt < 4; ++nt) {
        const float bv = bias[16 * nt + l16];
#pragma unroll
        for (int mt = 0; mt < 4; ++mt) {
            acc[mt][nt][0] = bv; acc[mt][nt][1] = bv;
            acc[mt][nt][2] = bv; acc[mt][nt][3] = bv;
        }
    }
    bf16x8 a[2][4], b[2][4];
#pragma unroll
    for (int kq = 0; kq < 2; ++kq) {
        const int k0 = 32 * kq + 8 * quad;
#pragma unroll
        for (int mt = 0; mt < 4; ++mt)
            a[kq][mt] = __builtin_bit_cast(bf16x8, *(const uint4*)(A + (16 * mt + l16) * 72 + k0));
#pragma unroll
        for (int nt = 0; nt < 4; ++nt)
            b[kq][nt] = __builtin_bit_cast(bf16x8, *(const uint4*)(Wg + (16 * nt + l16) * 64 + k0));
    }
#pragma unroll
    for (int kq = 0; kq < 2; ++kq)
#pragma unroll
        for (int mt = 0; mt < 4; ++mt)
#pragma unroll
            for (int nt = 0; nt < 4; ++nt)
                acc[mt][nt] = __builtin_amdgcn_mfma_f32_16x16x32_bf16(a[kq][mt], b[kq][nt], acc[mt][nt], 0, 0, 0);
    __syncthreads();   // all reads of A drained before in-place overwrite
#pragma unroll
    for (int mt = 0; mt < 4; ++mt)
#pragma unroll
        for (int nt = 0; nt < 4; ++nt)
#pragma unroll
            for (int reg = 0; reg < 4; ++reg) {
                const float v = fmaxf(acc[mt][nt][reg], 0.f);
                A[(16 * mt + 4 * quad + reg) * 72 + 16 * nt + l16] =
                    (unsigned short)f2bf_u(v);
            }
    __syncthreads();
}

__global__ __launch_bounds__(64) void sample_kernel(
    const float* __restrict__ ro, const float* __restrict__ rd, const float* __restrict__ vd,
    const unsigned short* __restrict__ featb, const float4* __restrict__ nrm4,
    const unsigned short* __restrict__ m0t, const float* __restrict__ mb0,
    const unsigned short* __restrict__ m1t, const float* __restrict__ mb1,
    const unsigned short* __restrict__ m2t, const float* __restrict__ mb2,
    const float* __restrict__ mw3, const float* __restrict__ mb3,
    float* __restrict__ sbuf, const int total)
{
    __shared__ __align__(16) unsigned short act[64 * 72];   // 9.2 KB, in-place

    const int t = threadIdx.x;          // 0..63, one wave
    const int s = blockIdx.x * 64 + t;
    const bool live = (s < total);
    bool actv = false;
    float alpha = 0.f, ndx = 0.f, ndy = 0.f, ndz = 0.f;
    float nsx = 0.f, nsy = 0.f, nsz = 0.f, depth = 0.f;
    float hf[64];
#pragma unroll
    for (int q = 0; q < 64; ++q) hf[q] = 0.f;

    if (live) {
        const int r = s / S_SAMPLES;
        const int j = s - r * S_SAMPLES;

        const float ox = ro[r * 3 + 0], oy = ro[r * 3 + 1], oz = ro[r * 3 + 2];
        const float dx = rd[r * 3 + 0], dy = rd[r * 3 + 1], dz = rd[r * 3 + 2];
        const float vx = vd[r * 3 + 0], vy = vd[r * 3 + 1], vz = vd[r * 3 + 2];

        const float vecx = (dx == 0.f) ? 1e-6f : dx;
        const float vecy = (dy == 0.f) ? 1e-6f : dy;
        const float vecz = (dz == 0.f) ? 1e-6f : dz;
        const float rax = (1.f - ox) / vecx, rbx = (-1.f - ox) / vecx;
        const float ray2 = (1.f - oy) / vecy, rby = (-1.f - oy) / vecy;
        const float raz = (1.f - oz) / vecz, rbz = (-1.f - oz) / vecz;
        float tmin = fmaxf(fmaxf(fminf(rax, rbx), fminf(ray2, rby)), fminf(raz, rbz));
        float tmax = fminf(fminf(fmaxf(rax, rbx), fmaxf(ray2, rby)), fmaxf(raz, rbz));
        tmin = fminf(fmaxf(tmin, 0.2f), 6.0f);
        tmax = fminf(fmaxf(tmax, 0.2f), 6.0f);
        const bool mask_ray = (tmax <= tmin);

        const float ndr = sqrtf(dx * dx + dy * dy + dz * dz);
        const float interpx = tmin + (STEP_VOX * (float)j) / ndr;
        const float px = ox + dx * interpx;
        const float py = oy + dy * interpx;
        const float pz = oz + dz * interpx;
        const bool outbox = mask_ray || (px < -1.f) || (px > 1.f) || (py < -1.f) ||
                            (py > 1.f) || (pz < -1.f) || (pz > 1.f);
        actv = !outbox;
        if (actv) {
            const float ux = fminf(fmaxf((px + 1.f) * 63.5f, 0.f), 127.f);
            const float uy = fminf(fmaxf((py + 1.f) * 63.5f, 0.f), 127.f);
            const float uz = fminf(fmaxf((pz + 1.f) * 63.5f, 0.f), 127.f);
            const int ix = min(max((int)floorf(ux), 0), 126);
            const int iy = min(max((int)floorf(uy), 0), 126);
            const int iz = min(max((int)floorf(uz), 0), 126);
            const float fx = ux - (float)ix, fy = uy - (float)iy, fz = uz - (float)iz;

            float lat[15];
#pragma unroll
            for (int q = 0; q < 15; ++q) lat[q] = 0.f;
            float na0 = 0.f, na1 = 0.f, na2 = 0.f;
            float c0v[8];
#pragma unroll
            for (int cn = 0; cn < 8; ++cn) {
                const int adx = cn >> 2, ady = (cn >> 1) & 1, adz = cn & 1;
                const int vox = ((ix + adx) * 128 + (iy + ady)) * 128 + (iz + adz);
                const float w = (adx ? fx : 1.f - fx) * (ady ? fy : 1.f - fy) * (adz ? fz : 1.f - fz);
                const float4 nd4 = nrm4[vox];
                c0v[cn] = nd4.w;
                const uint4* cp = (const uint4*)(featb + (size_t)vox * 16);
                const uint4 q0 = cp[0], q1 = cp[1];
                lat[0]  = fmaf(w, bf_hi(q0.x), lat[0]);
                lat[1]  = fmaf(w, bf_lo(q0.y), lat[1]);
                lat[2]  = fmaf(w, bf_hi(q0.y), lat[2]);
                lat[3]  = fmaf(w, bf_lo(q0.z), lat[3]);
                lat[4]  = fmaf(w, bf_hi(q0.z), lat[4]);
                lat[5]  = fmaf(w, bf_lo(q0.w), lat[5]);
                lat[6]  = fmaf(w, bf_hi(q0.w), lat[6]);
                lat[7]  = fmaf(w, bf_lo(q1.x), lat[7]);
                lat[8]  = fmaf(w, bf_hi(q1.x), lat[8]);
                lat[9]  = fmaf(w, bf_lo(q1.y), lat[9]);
                lat[10] = fmaf(w, bf_hi(q1.y), lat[10]);
                lat[11] = fmaf(w, bf_lo(q1.z), lat[11]);
                lat[12] = fmaf(w, bf_hi(q1.z), lat[12]);
                lat[13] = fmaf(w, bf_lo(q1.w), lat[13]);
                lat[14] = fmaf(w, bf_hi(q1.w), lat[14]);
                na0 = fmaf(w, nd4.x, na0);
                na1 = fmaf(w, nd4.y, na1);
                na2 = fmaf(w, nd4.z, na2);
            }

            const float c00 = c0v[0] * (1.f - fz) + c0v[1] * fz;
            const float c01 = c0v[2] * (1.f - fz) + c0v[3] * fz;
            const float c10 = c0v[4] * (1.f - fz) + c0v[5] * fz;
            const float c11 = c0v[6] * (1.f - fz) + c0v[7] * fz;
            const float e0 = c00 * (1.f - fy) + c01 * fy;
            const float e1 = c10 * (1.f - fy) + c11 * fy;
            const float d0 = e0 * (1.f - fx) + e1 * fx;
            const float dfx = e1 - e0;
            const float dfy = (c01 - c00) * (1.f - fx) + (c11 - c10) * fx;
            const float dfz = ((c0v[1] - c0v[0]) * (1.f - fy) + (c0v[3] - c0v[2]) * fy) * (1.f - fx)
                            + ((c0v[5] - c0v[4]) * (1.f - fy) + (c0v[7] - c0v[6]) * fy) * fx;

            const float zin = d0 + ACT_SHIFT;
            const float splus = fmaxf(zin, 0.f) + log1pf(__expf(-fabsf(zin)));
            const float e = __expf(-splus * 0.5f);
            alpha = 1.f - e;
            const float sig = 1.f / (1.f + __expf(-zin));
            const float dad = e * 0.5f * sig;
            const float gx = dad * dfx * 63.5f;
            const float gy = dad * dfy * 63.5f;
            const float gz = dad * dfz * 63.5f;
            const float gn = sqrtf(gx * gx + gy * gy + gz * gz);
            const float gi = 1.f / fmaxf(gn, 1e-12f);
            ndx = -gx * gi; ndy = -gy * gi; ndz = -gz * gi;

            const float nn = sqrtf(na0 * na0 + na1 * na1 + na2 * na2);
            const float ni = 1.f / fmaxf(nn, 1e-12f);
            nsx = -na0 * ni; nsy = -na1 * ni; nsz = -na2 * ni;

            const float dotv = -(vx * ndx + vy * ndy + vz * ndz);
            const float rx = 2.f * dotv * ndx + vx;
            const float ry = 2.f * dotv * ndy + vy;
            const float rz = 2.f * dotv * ndz + vz;

#pragma unroll
            for (int q = 0; q < 15; ++q) hf[q] = lat[q];
            hf[15] = rx; hf[16] = ry; hf[17] = rz;
#pragma unroll
            for (int fi = 0; fi < 6; ++fi) {
                const float fr = (float)(1 << fi);
                hf[18 + fi * 6 + 0] = __sinf(rx * fr);
                hf[18 + fi * 6 + 1] = __sinf(ry * fr);
                hf[18 + fi * 6 + 2] = __sinf(rz * fr);
                hf[18 + fi * 6 + 3] = __cosf(rx * fr);
                hf[18 + fi * 6 + 4] = __cosf(ry * fr);
                hf[18 + fi * 6 + 5] = __cosf(rz * fr);
            }
            depth = interpx * ndr;
        }
    }

#pragma unroll
    for (int q = 0; q < 8; ++q) {
        uint4 st;
        st.x = f2bf_u(hf[8 * q + 0]) | (f2bf_u(hf[8 * q + 1]) << 16);
        st.y = f2bf_u(hf[8 * q + 2]) | (f2bf_u(hf[8 * q + 3]) << 16);
        st.z = f2bf_u(hf[8 * q + 4]) | (f2bf_u(hf[8 * q + 5]) << 16);
        st.w = f2bf_u(hf[8 * q + 6]) | (f2bf_u(hf[8 * q + 7]) << 16);
        *(uint4*)(act + t * 72 + 8 * q) = st;
    }
    __syncthreads();

    mfma_layer(act, m0t, mb0, t);
    mfma_layer(act, m1t, mb1, t);
    mfma_layer(act, m2t, mb2, t);

    if (live) {
        float* so = sbuf + (size_t)s * 12;
        if (actv) {
            float r0 = mb3[0], r1 = mb3[1], r2 = mb3[2];
            const unsigned short* hr = act + t * 72;
#pragma unroll
            for (int c8 = 0; c8 < 8; ++c8) {
                const uint4 hu = *(const uint4*)(hr + 8 * c8);
                const float h[8] = {bf_lo(hu.x), bf_hi(hu.x), bf_lo(hu.y), bf_hi(hu.y),
                                    bf_lo(hu.z), bf_hi(hu.z), bf_lo(hu.w), bf_hi(hu.w)};
#pragma unroll
                for (int u = 0; u < 8; ++u) {
                    const int c = 8 * c8 + u;
                    r0 = fmaf(h[u], mw3[c * 3 + 0], r0);
                    r1 = fmaf(h[u], mw3[c * 3 + 1], r1);
                    r2 = fmaf(h[u], mw3[c * 3 + 2], r2);
                }
            }
            so[0] = alpha;
            so[1] = 1.f / (1.f + __expf(-r0));
            so[2] = 1.f / (1.f + __expf(-r1));
            so[3] = 1.f / (1.f + __expf(-r2));
            so[4] = ndx; so[5] = ndy; so[6] = ndz;
            so[7] = nsx; so[8] = nsy; so[9] = nsz;
            so[10] = depth;
            so[11] = 0.f;
        } else {
#pragma unroll
            for (int q = 0; q < 12; ++q) so[q] = 0.f;
        }
    }
}

// ============================================================================
// Kernel 4: per-ray compositing — coalesced chunk-strided single pass.
// ============================================================================
__global__ __launch_bounds__(64) void reduce_kernel(const float* __restrict__ sbuf,
                                                    float* __restrict__ out)
{
    const int r = blockIdx.x;
    const int lane = threadIdx.x;
    const int nchunks = (S_SAMPLES + 63) / 64;   // 7

    float R = 1.f;   // product of factors in all previous chunks (wave-uniform)
    float s0 = 0, s1 = 0, s2 = 0, s3 = 0, s4 = 0, s5 = 0, s6 = 0, s7 = 0, s8 = 0, s9 = 0, s10 = 0;

    for (int i = 0; i < nchunks; ++i) {
        const int j = i * 64 + lane;
        float4 q0 = make_float4(0.f, 0.f, 0.f, 0.f);
        float4 q1 = make_float4(0.f, 0.f, 0.f, 0.f);
        float4 q2 = make_float4(0.f, 0.f, 0.f, 0.f);
        float a = 0.f, fac = 1.f;
        if (j < S_SAMPLES) {
            const float* sp_ = sbuf + ((size_t)r * S_SAMPLES + j) * 12;
            q0 = *(const float4*)sp_;          // alpha, rgb0, rgb1, rgb2
            q1 = *(const float4*)(sp_ + 4);    // ndx, ndy, ndz, nsx
            q2 = *(const float4*)(sp_ + 8);    // nsy, nsz, depth, pad
            a = q0.x;
            fac = fmaxf(1.f - a, 1e-10f);
        }
        float scan = fac;
#pragma unroll
        for (int off = 1; off < 64; off <<= 1) {
            const float nv = __shfl_up(scan, (unsigned)off, 64);
            if (lane >= off) scan *= nv;
        }
        float pref = __shfl_up(scan, 1u, 64);
        if (lane == 0) pref = 1.f;
        pref *= R;
        const float w = a * pref;
        s0 = fmaf(w, q0.y, s0);
        s1 = fmaf(w, q0.z, s1);
        s2 = fmaf(w, q0.w, s2);
        s3 = fmaf(w, q2.z, s3);     // depth
        s4 += w;
        s5 = fmaf(w, q1.x, s5);     // nd
        s6 = fmaf(w, q1.y, s6);
        s7 = fmaf(w, q1.z, s7);
        s8 = fmaf(w, q1.w, s8);     // ns
        s9 = fmaf(w, q2.x, s9);
        s10 = fmaf(w, q2.y, s10);
        R *= __shfl(scan, 63, 64);
    }

#pragma unroll
    for (int m = 32; m >= 1; m >>= 1) {
        s0 += __shfl_xor(s0, m, 64);
        s1 += __shfl_xor(s1, m, 64);
        s2 += __shfl_xor(s2, m, 64);
        s3 += __shfl_xor(s3, m, 64);
        s4 += __shfl_xor(s4, m, 64);
        s5 += __shfl_xor(s5, m, 64);
        s6 += __shfl_xor(s6, m, 64);
        s7 += __shfl_xor(s7, m, 64);
        s8 += __shfl_xor(s8, m, 64);
        s9 += __shfl_xor(s9, m, 64);
        s10 += __shfl_xor(s10, m, 64);
    }
    if (lane == 0) {
        const float total = R;
        const float dm = s3 + total * 6.0f;
        out[r * 12 + 0] = s0 + total;
        out[r * 12 + 1] = s1 + total;
        out[r * 12 + 2] = s2 + total;
        out[r * 12 + 3] = dm;
        out[r * 12 + 4] = 1.f / dm;
        out[r * 12 + 5] = s4;
        out[r * 12 + 6] = s5; out[r * 12 + 7] = s6; out[r * 12 + 8] = s7;
        out[r * 12 + 9] = s8; out[r * 12 + 10] = s9; out[r * 12 + 11] = s10;
    }
}

// ============================================================================
extern "C" void kernel_launch(void* const* d_in, const int* in_sizes, int n_in,
                              void* d_out, int out_size, void* d_ws, size_t ws_size,
                              hipStream_t stream)
{
    (void)n_in; (void)out_size; (void)ws_size;
    const float* rays_o   = (const float*)d_in[0];
    const float* rays_d   = (const float*)d_in[1];
    const float* viewdirs = (const float*)d_in[2];
    const float* grid     = (const float*)d_in[3];
    const float* c1_w  = (const float*)d_in[4];
    const float* c1_b  = (const float*)d_in[5];
    const float* bn1_g = (const float*)d_in[6];
    const float* bn1_b = (const float*)d_in[7];
    const float* pr1_a = (const float*)d_in[8];
    const float* c2_w  = (const float*)d_in[9];
    const float* c2_b  = (const float*)d_in[10];
    const float* bn2_g = (const float*)d_in[11];
    const float* bn2_b = (const float*)d_in[12];
    const float* pr2_a = (const float*)d_in[13];
    const float* c3_w  = (const float*)d_in[14];
    const float* c3_b  = (const float*)d_in[15];
    const float* mw0 = (const float*)d_in[16];
    const float* mb0 = (const float*)d_in[17];
    const float* mw1 = (const float*)d_in[18];
    const float* mb1 = (const float*)d_in[19];
    const float* mw2 = (const float*)d_in[20];
    const float* mb2 = (const float*)d_in[21];
    const float* mw3 = (const float*)d_in[22];
    const float* mb3 = (const float*)d_in[23];

    const int N = in_sizes[0] / 3;   // 1024 rays
    const int total = N * S_SAMPLES;

    // ws layout (float units):
    // featb [0,16777216) | dens [16777216,18874368) |
    // nrm4 f4 [18874368,27262976) | zbuf f2 [27262976,31457280) |
    // cbuf f4 [31457280,39845888) | sbuf [39845888,45337600) | weights after
    float* wsf = (float*)d_ws;
    unsigned short* featb = (unsigned short*)wsf;
    float* dens    = wsf + (size_t)16777216;
    float4* nrm4   = (float4*)(wsf + (size_t)18874368);
    float2* zbuf   = (float2*)(wsf + (size_t)27262976);
    float4* cbuf   = (float4*)(wsf + (size_t)31457280);
    float* sbuf    = wsf + (size_t)39845888;
    float* b3p = wsf + (size_t)45337600;
    unsigned short* w1b = (unsigned short*)(wsf + (size_t)45337728);   // 2048 bf16
    unsigned short* w2b = (unsigned short*)(wsf + (size_t)45338752);   // 6144 bf16
    unsigned short* w3b = (unsigned short*)(wsf + (size_t)45341824);   // 20480 bf16
    unsigned short* m0t = (unsigned short*)(wsf + (size_t)45352064);
    unsigned short* m1t = (unsigned short*)(wsf + (size_t)45354112);
    unsigned short* m2t = (unsigned short*)(wsf + (size_t)45356160);

    prep_kernel<<<64, 256, 0, stream>>>(c1_w, c2_w, c3_w, c3_b, mw0, mw1, mw2,
                                        w1b, w2b, w3b, b3p, m0t, m1t, m2t);
    conv_fused_kernel<<<8192, 64, 0, stream>>>(grid, w1b, c1_b, bn1_g, bn1_b, pr1_a,
                                               w2b, c2_b, bn2_g, bn2_b, pr2_a,
                                               w3b, b3p, featb, dens);
    sobelZ_kernel<<<8192, 256, 0, stream>>>(dens, zbuf);
    sobelY_kernel<<<8192, 256, 0, stream>>>(zbuf, cbuf);
    sobelX_kernel<<<8192, 256, 0, stream>>>(cbuf, dens, nrm4);
    const int sblocks = (total + 63) / 64;
    sample_kernel<<<sblocks, 64, 0, stream>>>(rays_o, rays_d, viewdirs, featb, nrm4,
                                              m0t, mb0, m1t, mb1, m2t, mb2, mw3, mb3,
                                              sbuf, total);
    reduce_kernel<<<N, 64, 0, stream>>>(sbuf, (float*)d_out);
}